// Round 5
// baseline (293.779 us; speedup 1.0000x reference)
//
#include <hip/hip_runtime.h>
#include <math.h>

#define N_NODES 50000
#define N_EDGES 800000

typedef __attribute__((ext_vector_type(8))) short bf16x8;
typedef __attribute__((ext_vector_type(4))) float f32x4;

// round-to-nearest-even float -> bf16
__device__ __forceinline__ short f2bf(float f) {
  union { float f; unsigned u; } v; v.f = f;
  unsigned r = v.u + 0x7FFFu + ((v.u >> 16) & 1u);
  return (short)(r >> 16);
}

// tanh-gelu (jax approximate=True). Overflow-safe (e=inf -> gelu=h).
__device__ __forceinline__ float gelu_f(float h) {
  const float m1 = h * h;
  const float t2u = h * fmaf(0.07135481f, m1, 1.5957691f);
  const float e = __expf(t2u);
  const float rc = __builtin_amdgcn_rcpf(1.f + e);
  return h - h * rc;
}

#define PIN(v) asm volatile("" : "+v"(v))

// ---------------------------------------------------------------------------
// Kernel 1: AB[n][c] = x[n] @ Wab[:,c] + 0.5*b1[c mod 128]
// (unchanged from round 4 — ~25 us, not the bottleneck)
// ---------------------------------------------------------------------------
__global__ __launch_bounds__(256) void node_kernel(
    const float* __restrict__ x, const float* __restrict__ W1,
    const float* __restrict__ b1, float* __restrict__ AB) {
  const int l = threadIdx.x & 63;
  const int wv = threadIdx.x >> 6;
  const int r = l & 15, g4 = l >> 4;

  const int wid = blockIdx.x * 4 + wv;
  const int s = wid & 3;

  bf16x8 wA[4][4];
#pragma unroll
  for (int q = 0; q < 4; ++q) {
    const int c = 16 * (4 * s + q) + r;
    const float* Wb = (c < 128) ? (W1 + c) : (W1 + 128 * 128 + (c - 128));
#pragma unroll
    for (int ks = 0; ks < 4; ++ks) {
#pragma unroll
      for (int t = 0; t < 8; ++t)
        wA[q][ks][t] = f2bf(Wb[(size_t)(ks * 32 + g4 * 8 + t) * 128]);
      PIN(wA[q][ks]);
    }
  }
  float4 bv[4];
#pragma unroll
  for (int q = 0; q < 4; ++q)
    bv[q] = *(const float4*)(b1 + ((16 * (4 * s + q) + g4 * 4) & 127));

  for (int t0 = wid >> 2; t0 < (N_NODES / 16); t0 += 1024) {
    const int n0 = t0 * 16;
    f32x4 acc[4] = {{0,0,0,0},{0,0,0,0},{0,0,0,0},{0,0,0,0}};
#pragma unroll
    for (int ks = 0; ks < 4; ++ks) {
      const float* xr = x + (size_t)(n0 + r) * 128 + ks * 32 + g4 * 8;
      const float4 x0 = *(const float4*)xr;
      const float4 x1 = *(const float4*)(xr + 4);
      bf16x8 xb;
      xb[0] = f2bf(x0.x); xb[1] = f2bf(x0.y); xb[2] = f2bf(x0.z); xb[3] = f2bf(x0.w);
      xb[4] = f2bf(x1.x); xb[5] = f2bf(x1.y); xb[6] = f2bf(x1.z); xb[7] = f2bf(x1.w);
#pragma unroll
      for (int q = 0; q < 4; ++q)
        acc[q] = __builtin_amdgcn_mfma_f32_16x16x32_bf16(wA[q][ks], xb, acc[q], 0, 0, 0);
    }
#pragma unroll
    for (int q = 0; q < 4; ++q) {
      float4 o;
      o.x = acc[q][0] + 0.5f * bv[q].x;
      o.y = acc[q][1] + 0.5f * bv[q].y;
      o.z = acc[q][2] + 0.5f * bv[q].z;
      o.w = acc[q][3] + 0.5f * bv[q].w;
      *(float4*)(AB + (size_t)(n0 + r) * 256 + 16 * (4 * s + q) + g4 * 4) = o;
    }
  }
}

// ---------------------------------------------------------------------------
// Kernel 2: fused edge kernel. One wave = 16 edges.
// Round-5 changes vs round 4:
//  - nt loads for ea/edge_index streams, nt stores for out (keep AB in LLC)
//  - base-projection MFMAs deferred past the gate reduce (frees 32 acc VGPRs)
//  - software prefetch of next tile's indices + ea row (hides idx->gather chain)
// ---------------------------------------------------------------------------
__global__ __launch_bounds__(256) void edge_kernel(
    const float* __restrict__ edge_attr, const int* __restrict__ edge_index,
    const float* __restrict__ AB,
    const float* __restrict__ W_proj, const float* __restrict__ b_proj,
    const float* __restrict__ W1,
    const float* __restrict__ W2, const float* __restrict__ b2,
    float* __restrict__ out) {
  const int l = threadIdx.x & 63;
  const int wv = threadIdx.x >> 6;
  const int r = l & 15, g4 = l >> 4;

  bf16x8 wP[8], wH[8];
#pragma unroll
  for (int mb = 0; mb < 8; ++mb) {
    const int c = 16 * mb + r;
    bf16x8 p, h;
#pragma unroll
    for (int t = 0; t < 8; ++t) {
      const int kk = g4 * 8 + t;
      p[t] = (kk < 31) ? f2bf(W_proj[(size_t)kk * 128 + c]) : (short)0;
      h[t] = (kk < 31) ? f2bf(W1[(size_t)(256 + kk) * 128 + c]) : (short)0;
    }
    wP[mb] = p; wH[mb] = h;
    PIN(wP[mb]); PIN(wH[mb]);
  }
  const float b2v = b2[0];

  const int nwaves = gridDim.x * 4;
  const int NT = N_EDGES / 16;
  int tile = blockIdx.x * 4 + wv;
  if (tile >= NT) return;

  // ---- prefetch state for the current tile ----
  int src, dst;
  float eaf[8];
  {
    const int e = tile * 16 + r;
    src = __builtin_nontemporal_load(edge_index + e);
    dst = __builtin_nontemporal_load(edge_index + N_EDGES + e);
    const float* ear = edge_attr + (size_t)e * 31 + g4 * 8;
#pragma unroll
    for (int t = 0; t < 8; ++t)
      eaf[t] = (g4 * 8 + t < 31) ? __builtin_nontemporal_load(ear + t) : 0.f;
  }

  for (; tile < NT; tile += nwaves) {
    const int e = tile * 16 + r;
    const int csrc = src, cdst = dst;
    bf16x8 eb;
#pragma unroll
    for (int t = 0; t < 8; ++t) eb[t] = f2bf(eaf[t]);

    // issue next tile's prefetch immediately (independent of this tile)
    const int tnext = tile + nwaves;
    if (tnext < NT) {
      const int en = tnext * 16 + r;
      src = __builtin_nontemporal_load(edge_index + en);
      dst = __builtin_nontemporal_load(edge_index + N_EDGES + en);
      const float* earn = edge_attr + (size_t)en * 31 + g4 * 8;
#pragma unroll
      for (int t = 0; t < 8; ++t)
        if (g4 * 8 + t < 31) eaf[t] = __builtin_nontemporal_load(earn + t);
    }

    // gathers init the h accumulator (b1 baked into AB)
    const float* arow = AB + (size_t)csrc * 256 + g4 * 4;
    const float* brow = AB + (size_t)cdst * 256 + 128 + g4 * 4;
    f32x4 acch[8];
#pragma unroll
    for (int mb = 0; mb < 8; ++mb) {
      const float4 ga = *(const float4*)(arow + 16 * mb);
      const float4 gb = *(const float4*)(brow + 16 * mb);
      f32x4 c; c[0] = ga.x + gb.x; c[1] = ga.y + gb.y;
      c[2] = ga.z + gb.z; c[3] = ga.w + gb.w;
      acch[mb] = c;
    }
#pragma unroll
    for (int mb = 0; mb < 8; ++mb)
      acch[mb] = __builtin_amdgcn_mfma_f32_16x16x32_bf16(wH[mb], eb, acch[mb], 0, 0, 0);

    // gate logit: lane holds cols j = 16*mb + g4*4 + i of its edge
    float lg = 0.f;
#pragma unroll
    for (int mb = 0; mb < 8; ++mb) {
      const float4 w2v = *(const float4*)(W2 + 16 * mb + g4 * 4);
      lg = fmaf(gelu_f(acch[mb][0]), w2v.x, lg);
      lg = fmaf(gelu_f(acch[mb][1]), w2v.y, lg);
      lg = fmaf(gelu_f(acch[mb][2]), w2v.z, lg);
      lg = fmaf(gelu_f(acch[mb][3]), w2v.w, lg);
    }
    lg += __shfl_xor(lg, 16);
    lg += __shfl_xor(lg, 32);
    const float gate = __builtin_amdgcn_rcpf(1.f + __expf(-(lg + b2v)));

    // deferred base projection: compute per-mb and stream out (nt)
    float* orow = out + (size_t)e * 128 + g4 * 4;
#pragma unroll
    for (int mb = 0; mb < 8; ++mb) {
      f32x4 ac = __builtin_amdgcn_mfma_f32_16x16x32_bf16(
          wP[mb], eb, (f32x4){0.f, 0.f, 0.f, 0.f}, 0, 0, 0);
      const float4 bp = *(const float4*)(b_proj + 16 * mb + g4 * 4);
      f32x4 o;
      o[0] = (ac[0] + bp.x) * gate;
      o[1] = (ac[1] + bp.y) * gate;
      o[2] = (ac[2] + bp.z) * gate;
      o[3] = (ac[3] + bp.w) * gate;
      __builtin_nontemporal_store(o, (f32x4*)(orow + 16 * mb));
    }
  }
}

extern "C" void kernel_launch(void* const* d_in, const int* in_sizes, int n_in,
                              void* d_out, int out_size, void* d_ws, size_t ws_size,
                              hipStream_t stream) {
  const float* x          = (const float*)d_in[0];
  const float* edge_attr  = (const float*)d_in[1];
  const int*   edge_index = (const int*)d_in[2];
  const float* W_proj     = (const float*)d_in[3];
  const float* b_proj     = (const float*)d_in[4];
  const float* W1         = (const float*)d_in[5];
  const float* b1         = (const float*)d_in[6];
  const float* W2         = (const float*)d_in[7];
  const float* b2         = (const float*)d_in[8];
  float* out = (float*)d_out;
  float* AB  = (float*)d_ws;   // 50000*256 f32 = 51.2 MB

  hipLaunchKernelGGL(node_kernel, dim3(1024), dim3(256), 0, stream,
                     x, W1, b1, AB);
  hipLaunchKernelGGL(edge_kernel, dim3(2048), dim3(256), 0, stream,
                     edge_attr, edge_index, AB, W_proj, b_proj, W1, W2, b2,
                     out);
}

// Round 6
// 234.319 us; speedup vs baseline: 1.2538x; 1.2538x over previous
//
#include <hip/hip_runtime.h>
#include <math.h>

#define N_NODES 50000
#define N_EDGES 800000

typedef __attribute__((ext_vector_type(8))) short bf16x8;
typedef __attribute__((ext_vector_type(4))) float f32x4;

// round-to-nearest-even float -> bf16
__device__ __forceinline__ short f2bf(float f) {
  union { float f; unsigned u; } v; v.f = f;
  unsigned r = v.u + 0x7FFFu + ((v.u >> 16) & 1u);
  return (short)(r >> 16);
}

// tanh-gelu (jax approximate=True). Overflow-safe (e=inf -> gelu=h).
__device__ __forceinline__ float gelu_f(float h) {
  const float m1 = h * h;
  const float t2u = h * fmaf(0.07135481f, m1, 1.5957691f);
  const float e = __expf(t2u);
  const float rc = __builtin_amdgcn_rcpf(1.f + e);
  return h - h * rc;
}

#define PIN(v) asm volatile("" : "+v"(v))

// ---------------------------------------------------------------------------
// Kernel 1: AB[n][c] = x[n] @ Wab[:,c] + 0.5*b1[c mod 128]   (unchanged)
// ---------------------------------------------------------------------------
__global__ __launch_bounds__(256) void node_kernel(
    const float* __restrict__ x, const float* __restrict__ W1,
    const float* __restrict__ b1, float* __restrict__ AB) {
  const int l = threadIdx.x & 63;
  const int wv = threadIdx.x >> 6;
  const int r = l & 15, g4 = l >> 4;

  const int wid = blockIdx.x * 4 + wv;
  const int s = wid & 3;

  bf16x8 wA[4][4];
#pragma unroll
  for (int q = 0; q < 4; ++q) {
    const int c = 16 * (4 * s + q) + r;
    const float* Wb = (c < 128) ? (W1 + c) : (W1 + 128 * 128 + (c - 128));
#pragma unroll
    for (int ks = 0; ks < 4; ++ks) {
#pragma unroll
      for (int t = 0; t < 8; ++t)
        wA[q][ks][t] = f2bf(Wb[(size_t)(ks * 32 + g4 * 8 + t) * 128]);
      PIN(wA[q][ks]);
    }
  }
  float4 bv[4];
#pragma unroll
  for (int q = 0; q < 4; ++q)
    bv[q] = *(const float4*)(b1 + ((16 * (4 * s + q) + g4 * 4) & 127));

  for (int t0 = wid >> 2; t0 < (N_NODES / 16); t0 += 1024) {
    const int n0 = t0 * 16;
    f32x4 acc[4] = {{0,0,0,0},{0,0,0,0},{0,0,0,0},{0,0,0,0}};
#pragma unroll
    for (int ks = 0; ks < 4; ++ks) {
      const float* xr = x + (size_t)(n0 + r) * 128 + ks * 32 + g4 * 8;
      const float4 x0 = *(const float4*)xr;
      const float4 x1 = *(const float4*)(xr + 4);
      bf16x8 xb;
      xb[0] = f2bf(x0.x); xb[1] = f2bf(x0.y); xb[2] = f2bf(x0.z); xb[3] = f2bf(x0.w);
      xb[4] = f2bf(x1.x); xb[5] = f2bf(x1.y); xb[6] = f2bf(x1.z); xb[7] = f2bf(x1.w);
#pragma unroll
      for (int q = 0; q < 4; ++q)
        acc[q] = __builtin_amdgcn_mfma_f32_16x16x32_bf16(wA[q][ks], xb, acc[q], 0, 0, 0);
    }
#pragma unroll
    for (int q = 0; q < 4; ++q) {
      float4 o;
      o.x = acc[q][0] + 0.5f * bv[q].x;
      o.y = acc[q][1] + 0.5f * bv[q].y;
      o.z = acc[q][2] + 0.5f * bv[q].z;
      o.w = acc[q][3] + 0.5f * bv[q].w;
      *(float4*)(AB + (size_t)(n0 + r) * 256 + 16 * (4 * s + q) + g4 * 4) = o;
    }
  }
}

// ---------------------------------------------------------------------------
// Kernel 2: fused edge kernel. One wave = 16 edges.
// Round-6 changes vs round 5:
//  - revert nt LOADS (ea rows share cache lines) and explicit prefetch
//  - keep deferred base-projection MFMAs (register relief)
//  - NEW: wave-private LDS transpose of the 16x128 out-tile, then nt stores
//    where each instruction covers a contiguous 1 KB block (full HBM lines,
//    no write amplification, and the 400 MB write stream stops evicting AB
//    from the LLC between gathers)
// ---------------------------------------------------------------------------
#define ROWD 132  // padded row stride in dwords (16B-aligned, bank-floor)

__global__ __launch_bounds__(256) void edge_kernel(
    const float* __restrict__ edge_attr, const int* __restrict__ edge_index,
    const float* __restrict__ AB,
    const float* __restrict__ W_proj, const float* __restrict__ b_proj,
    const float* __restrict__ W1,
    const float* __restrict__ W2, const float* __restrict__ b2,
    float* __restrict__ out) {
  __shared__ float tlds[4][16 * ROWD];
  const int l = threadIdx.x & 63;
  const int wv = threadIdx.x >> 6;
  const int r = l & 15, g4 = l >> 4;
  float* const tl = &tlds[wv][0];

  bf16x8 wP[8], wH[8];
#pragma unroll
  for (int mb = 0; mb < 8; ++mb) {
    const int c = 16 * mb + r;
    bf16x8 p, h;
#pragma unroll
    for (int t = 0; t < 8; ++t) {
      const int kk = g4 * 8 + t;
      p[t] = (kk < 31) ? f2bf(W_proj[(size_t)kk * 128 + c]) : (short)0;
      h[t] = (kk < 31) ? f2bf(W1[(size_t)(256 + kk) * 128 + c]) : (short)0;
    }
    wP[mb] = p; wH[mb] = h;
    PIN(wP[mb]); PIN(wH[mb]);
  }
  const float b2v = b2[0];

  const int nwaves = gridDim.x * 4;
  const int NT = N_EDGES / 16;

  for (int tile = blockIdx.x * 4 + wv; tile < NT; tile += nwaves) {
    const int e = tile * 16 + r;
    const int src = edge_index[e];
    const int dst = edge_index[N_EDGES + e];

    // ea B-frag: b[t] = ea[e][g4*8+t], k=31 pad -> 0
    const float* ear = edge_attr + (size_t)e * 31 + g4 * 8;
    bf16x8 eb;
#pragma unroll
    for (int t = 0; t < 8; ++t) {
      const int kk = g4 * 8 + t;
      eb[t] = (kk < 31) ? f2bf(ear[t]) : (short)0;
    }

    // gathers init the h accumulator (b1 baked into AB)
    const float* arow = AB + (size_t)src * 256 + g4 * 4;
    const float* brow = AB + (size_t)dst * 256 + 128 + g4 * 4;
    f32x4 acch[8];
#pragma unroll
    for (int mb = 0; mb < 8; ++mb) {
      const float4 ga = *(const float4*)(arow + 16 * mb);
      const float4 gb = *(const float4*)(brow + 16 * mb);
      f32x4 c; c[0] = ga.x + gb.x; c[1] = ga.y + gb.y;
      c[2] = ga.z + gb.z; c[3] = ga.w + gb.w;
      acch[mb] = c;
    }
#pragma unroll
    for (int mb = 0; mb < 8; ++mb)
      acch[mb] = __builtin_amdgcn_mfma_f32_16x16x32_bf16(wH[mb], eb, acch[mb], 0, 0, 0);

    // gate logit: lane holds cols j = 16*mb + g4*4 + i of its edge
    float lg = 0.f;
#pragma unroll
    for (int mb = 0; mb < 8; ++mb) {
      const float4 w2v = *(const float4*)(W2 + 16 * mb + g4 * 4);
      lg = fmaf(gelu_f(acch[mb][0]), w2v.x, lg);
      lg = fmaf(gelu_f(acch[mb][1]), w2v.y, lg);
      lg = fmaf(gelu_f(acch[mb][2]), w2v.z, lg);
      lg = fmaf(gelu_f(acch[mb][3]), w2v.w, lg);
    }
    lg += __shfl_xor(lg, 16);
    lg += __shfl_xor(lg, 32);
    const float gate = __builtin_amdgcn_rcpf(1.f + __expf(-(lg + b2v)));

    // deferred base projection -> LDS tile (wave-private, no barrier)
#pragma unroll
    for (int mb = 0; mb < 8; ++mb) {
      f32x4 ac = __builtin_amdgcn_mfma_f32_16x16x32_bf16(
          wP[mb], eb, (f32x4){0.f, 0.f, 0.f, 0.f}, 0, 0, 0);
      const float4 bp = *(const float4*)(b_proj + 16 * mb + g4 * 4);
      f32x4 o;
      o[0] = (ac[0] + bp.x) * gate;
      o[1] = (ac[1] + bp.y) * gate;
      o[2] = (ac[2] + bp.z) * gate;
      o[3] = (ac[3] + bp.w) * gate;
      *(f32x4*)(tl + ROWD * r + 16 * mb + 4 * g4) = o;
    }

    // read back transposed and stream out: instruction k covers one
    // contiguous 1 KB block (64 lanes x 16 B consecutive) -> full HBM lines
    float* const obase = out + (size_t)tile * 16 * 128;
#pragma unroll
    for (int k = 0; k < 8; ++k) {
      const f32x4 v = *(const f32x4*)(tl + ROWD * (2 * k + (l >> 5)) + 4 * (l & 31));
      __builtin_nontemporal_store(v, (f32x4*)(obase + 256 * k + 4 * l));
    }
  }
}

extern "C" void kernel_launch(void* const* d_in, const int* in_sizes, int n_in,
                              void* d_out, int out_size, void* d_ws, size_t ws_size,
                              hipStream_t stream) {
  const float* x          = (const float*)d_in[0];
  const float* edge_attr  = (const float*)d_in[1];
  const int*   edge_index = (const int*)d_in[2];
  const float* W_proj     = (const float*)d_in[3];
  const float* b_proj     = (const float*)d_in[4];
  const float* W1         = (const float*)d_in[5];
  const float* b1         = (const float*)d_in[6];
  const float* W2         = (const float*)d_in[7];
  const float* b2         = (const float*)d_in[8];
  float* out = (float*)d_out;
  float* AB  = (float*)d_ws;   // 50000*256 f32 = 51.2 MB

  hipLaunchKernelGGL(node_kernel, dim3(1024), dim3(256), 0, stream,
                     x, W1, b1, AB);
  hipLaunchKernelGGL(edge_kernel, dim3(2048), dim3(256), 0, stream,
                     edge_attr, edge_index, AB, W_proj, b_proj, W1, W2, b2,
                     out);
}

// Round 7
// 172.062 us; speedup vs baseline: 1.7074x; 1.3618x over previous
//
#include <hip/hip_runtime.h>
#include <math.h>

#define N_NODES 50000
#define N_EDGES 800000

typedef __attribute__((ext_vector_type(8))) short bf16x8;
typedef __attribute__((ext_vector_type(4))) float f32x4;

// round-to-nearest-even float -> bf16 (bits in low 16)
__device__ __forceinline__ unsigned f2bfu(float f) {
  union { float f; unsigned u; } v; v.f = f;
  return (v.u + 0x7FFFu + ((v.u >> 16) & 1u)) >> 16;
}
__device__ __forceinline__ short f2bf(float f) { return (short)f2bfu(f); }

__device__ __forceinline__ float bflo(unsigned d) {
  union { unsigned u; float f; } v; v.u = d << 16; return v.f;
}
__device__ __forceinline__ float bfhi(unsigned d) {
  union { unsigned u; float f; } v; v.u = d & 0xFFFF0000u; return v.f;
}

// tanh-gelu (jax approximate=True). Overflow-safe (e=inf -> gelu=h).
__device__ __forceinline__ float gelu_f(float h) {
  const float m1 = h * h;
  const float t2u = h * fmaf(0.07135481f, m1, 1.5957691f);
  const float e = __expf(t2u);
  const float rc = __builtin_amdgcn_rcpf(1.f + e);
  return h - h * rc;
}

#define PIN(v) asm volatile("" : "+v"(v))

// ---------------------------------------------------------------------------
// Kernel 1: AB (bf16, fragment-major layout).
//   value: Wab-column dot x[n] + 0.5*b1, Wab[k][c] = c<128 ? W1[k][c]
//                                                        : W1[128+k][c-128]
//   layout: AB[n][half][g4][mb8][i] (bf16), half=c>>7, col = 128*half +
//           16*mb8 + 4*g4 + i  -> exactly the edge kernel's MFMA C fragment
//           order, so each edge-lane gather is 64 B contiguous.
// ---------------------------------------------------------------------------
__global__ __launch_bounds__(256) void node_kernel(
    const float* __restrict__ x, const float* __restrict__ W1,
    const float* __restrict__ b1, unsigned short* __restrict__ AB) {
  const int l = threadIdx.x & 63;
  const int wv = threadIdx.x >> 6;
  const int r = l & 15, g4 = l >> 4;

  const int wid = blockIdx.x * 4 + wv;
  const int s = wid & 3;                 // col strip: blocks mb = 4s+q

  bf16x8 wA[4][4];
#pragma unroll
  for (int q = 0; q < 4; ++q) {
    const int c = 16 * (4 * s + q) + r;
    const float* Wb = (c < 128) ? (W1 + c) : (W1 + 128 * 128 + (c - 128));
#pragma unroll
    for (int ks = 0; ks < 4; ++ks) {
#pragma unroll
      for (int t = 0; t < 8; ++t)
        wA[q][ks][t] = f2bf(Wb[(size_t)(ks * 32 + g4 * 8 + t) * 128]);
      PIN(wA[q][ks]);
    }
  }
  float4 bv[4];
#pragma unroll
  for (int q = 0; q < 4; ++q)
    bv[q] = *(const float4*)(b1 + ((16 * (4 * s + q) + g4 * 4) & 127));

  const int half = s >> 1;

  for (int t0 = wid >> 2; t0 < (N_NODES / 16); t0 += 1024) {
    const int n0 = t0 * 16;
    f32x4 acc[4] = {{0,0,0,0},{0,0,0,0},{0,0,0,0},{0,0,0,0}};
#pragma unroll
    for (int ks = 0; ks < 4; ++ks) {
      const float* xr = x + (size_t)(n0 + r) * 128 + ks * 32 + g4 * 8;
      const float4 x0 = *(const float4*)xr;
      const float4 x1 = *(const float4*)(xr + 4);
      bf16x8 xb;
      xb[0] = f2bf(x0.x); xb[1] = f2bf(x0.y); xb[2] = f2bf(x0.z); xb[3] = f2bf(x0.w);
      xb[4] = f2bf(x1.x); xb[5] = f2bf(x1.y); xb[6] = f2bf(x1.z); xb[7] = f2bf(x1.w);
#pragma unroll
      for (int q = 0; q < 4; ++q)
        acc[q] = __builtin_amdgcn_mfma_f32_16x16x32_bf16(wA[q][ks], xb, acc[q], 0, 0, 0);
    }
#pragma unroll
    for (int q = 0; q < 4; ++q) {
      const int mb8 = 4 * (s & 1) + q;
      const float o0 = acc[q][0] + 0.5f * bv[q].x;
      const float o1 = acc[q][1] + 0.5f * bv[q].y;
      const float o2 = acc[q][2] + 0.5f * bv[q].z;
      const float o3 = acc[q][3] + 0.5f * bv[q].w;
      uint2 pk;
      pk.x = f2bfu(o0) | (f2bfu(o1) << 16);
      pk.y = f2bfu(o2) | (f2bfu(o3) << 16);
      *(uint2*)(AB + (size_t)(n0 + r) * 256 + half * 128 + g4 * 32 + mb8 * 4) = pk;
    }
  }
}

// ---------------------------------------------------------------------------
// Kernel 2: fused edge kernel. One wave = 16 edges.
// Round-7 changes vs round 6:
//  - AB gathers are bf16 fragment-major: 4 x uint4 (16 B) fully-coalesced
//    loads per half per lane (512 B/edge total, was 1 KB) -> gather L2/HBM
//    traffic halves, LLC table footprint halves (25.6 MB)
//  - unpack bf16 pairs with shift/mask (2 VALU per dword)
// Everything else (deferred base MFMA, LDS out-transpose, nt full-line
// stores) kept from round 6.
// ---------------------------------------------------------------------------
#define ROWD 132  // padded LDS row stride in dwords

__global__ __launch_bounds__(256) void edge_kernel(
    const float* __restrict__ edge_attr, const int* __restrict__ edge_index,
    const unsigned short* __restrict__ AB,
    const float* __restrict__ W_proj, const float* __restrict__ b_proj,
    const float* __restrict__ W1,
    const float* __restrict__ W2, const float* __restrict__ b2,
    float* __restrict__ out) {
  __shared__ float tlds[4][16 * ROWD];
  const int l = threadIdx.x & 63;
  const int wv = threadIdx.x >> 6;
  const int r = l & 15, g4 = l >> 4;
  float* const tl = &tlds[wv][0];

  bf16x8 wP[8], wH[8];
#pragma unroll
  for (int mb = 0; mb < 8; ++mb) {
    const int c = 16 * mb + r;
    bf16x8 p, h;
#pragma unroll
    for (int t = 0; t < 8; ++t) {
      const int kk = g4 * 8 + t;
      p[t] = (kk < 31) ? f2bf(W_proj[(size_t)kk * 128 + c]) : (short)0;
      h[t] = (kk < 31) ? f2bf(W1[(size_t)(256 + kk) * 128 + c]) : (short)0;
    }
    wP[mb] = p; wH[mb] = h;
    PIN(wP[mb]); PIN(wH[mb]);
  }
  const float b2v = b2[0];

  const int nwaves = gridDim.x * 4;
  const int NT = N_EDGES / 16;

  for (int tile = blockIdx.x * 4 + wv; tile < NT; tile += nwaves) {
    const int e = tile * 16 + r;
    const int src = edge_index[e];
    const int dst = edge_index[N_EDGES + e];

    // ea B-frag: b[t] = ea[e][g4*8+t], k=31 pad -> 0
    const float* ear = edge_attr + (size_t)e * 31 + g4 * 8;
    bf16x8 eb;
#pragma unroll
    for (int t = 0; t < 8; ++t) {
      const int kk = g4 * 8 + t;
      eb[t] = (kk < 31) ? f2bf(ear[t]) : (short)0;
    }

    // coalesced bf16 gathers: 64 B contiguous per lane per half
    const uint4* ap4 = (const uint4*)(AB + (size_t)src * 256 + g4 * 32);
    const uint4* bp4 = (const uint4*)(AB + (size_t)dst * 256 + 128 + g4 * 32);
    uint4 ua[4], ub[4];
#pragma unroll
    for (int t = 0; t < 4; ++t) { ua[t] = ap4[t]; ub[t] = bp4[t]; }

    // unpack + combine: acch[mb][i], mb = 2t + (elem>=4), dword pairs
    f32x4 acch[8];
#pragma unroll
    for (int t = 0; t < 4; ++t) {
      acch[2 * t][0]     = bflo(ua[t].x) + bflo(ub[t].x);
      acch[2 * t][1]     = bfhi(ua[t].x) + bfhi(ub[t].x);
      acch[2 * t][2]     = bflo(ua[t].y) + bflo(ub[t].y);
      acch[2 * t][3]     = bfhi(ua[t].y) + bfhi(ub[t].y);
      acch[2 * t + 1][0] = bflo(ua[t].z) + bflo(ub[t].z);
      acch[2 * t + 1][1] = bfhi(ua[t].z) + bfhi(ub[t].z);
      acch[2 * t + 1][2] = bflo(ua[t].w) + bflo(ub[t].w);
      acch[2 * t + 1][3] = bfhi(ua[t].w) + bfhi(ub[t].w);
    }
#pragma unroll
    for (int mb = 0; mb < 8; ++mb)
      acch[mb] = __builtin_amdgcn_mfma_f32_16x16x32_bf16(wH[mb], eb, acch[mb], 0, 0, 0);

    // gate logit: lane holds cols j = 16*mb + g4*4 + i of its edge
    float lg = 0.f;
#pragma unroll
    for (int mb = 0; mb < 8; ++mb) {
      const float4 w2v = *(const float4*)(W2 + 16 * mb + g4 * 4);
      lg = fmaf(gelu_f(acch[mb][0]), w2v.x, lg);
      lg = fmaf(gelu_f(acch[mb][1]), w2v.y, lg);
      lg = fmaf(gelu_f(acch[mb][2]), w2v.z, lg);
      lg = fmaf(gelu_f(acch[mb][3]), w2v.w, lg);
    }
    lg += __shfl_xor(lg, 16);
    lg += __shfl_xor(lg, 32);
    const float gate = __builtin_amdgcn_rcpf(1.f + __expf(-(lg + b2v)));

    // deferred base projection -> wave-private LDS tile (no barrier)
#pragma unroll
    for (int mb = 0; mb < 8; ++mb) {
      f32x4 ac = __builtin_amdgcn_mfma_f32_16x16x32_bf16(
          wP[mb], eb, (f32x4){0.f, 0.f, 0.f, 0.f}, 0, 0, 0);
      const float4 bp = *(const float4*)(b_proj + 16 * mb + g4 * 4);
      f32x4 o;
      o[0] = (ac[0] + bp.x) * gate;
      o[1] = (ac[1] + bp.y) * gate;
      o[2] = (ac[2] + bp.z) * gate;
      o[3] = (ac[3] + bp.w) * gate;
      *(f32x4*)(tl + ROWD * r + 16 * mb + 4 * g4) = o;
    }

    // transposed readback -> each nt store instruction covers contiguous 1 KB
    float* const obase = out + (size_t)tile * 16 * 128;
#pragma unroll
    for (int k = 0; k < 8; ++k) {
      const f32x4 v = *(const f32x4*)(tl + ROWD * (2 * k + (l >> 5)) + 4 * (l & 31));
      __builtin_nontemporal_store(v, (f32x4*)(obase + 256 * k + 4 * l));
    }
  }
}

extern "C" void kernel_launch(void* const* d_in, const int* in_sizes, int n_in,
                              void* d_out, int out_size, void* d_ws, size_t ws_size,
                              hipStream_t stream) {
  const float* x          = (const float*)d_in[0];
  const float* edge_attr  = (const float*)d_in[1];
  const int*   edge_index = (const int*)d_in[2];
  const float* W_proj     = (const float*)d_in[3];
  const float* b_proj     = (const float*)d_in[4];
  const float* W1         = (const float*)d_in[5];
  const float* b1         = (const float*)d_in[6];
  const float* W2         = (const float*)d_in[7];
  const float* b2         = (const float*)d_in[8];
  float* out = (float*)d_out;
  unsigned short* AB = (unsigned short*)d_ws;  // 50000*256 bf16 = 25.6 MB

  hipLaunchKernelGGL(node_kernel, dim3(1024), dim3(256), 0, stream,
                     x, W1, b1, AB);
  hipLaunchKernelGGL(edge_kernel, dim3(2048), dim3(256), 0, stream,
                     edge_attr, edge_index, AB, W_proj, b_proj, W1, W2, b2,
                     out);
}